// Round 2
// baseline (166.850 us; speedup 1.0000x reference)
//
#include <hip/hip_runtime.h>

// Problem constants (fixed by the reference file).
#define BB 16
#define HH 512
#define WW 512
#define PIX_PER_THREAD 2          // 2 px * 9 fp32 = 72 B per thread
#define THREADS_PER_BATCH ((HH * WW) / PIX_PER_THREAD)   // 131072 = 2^17
#define TOTAL_THREADS (BB * THREADS_PER_BATCH)           // 2097152 = 2^21
#define BLOCK 256
#define WORDS_PER_THREAD 18
#define WORDS_PER_BLOCK (BLOCK * WORDS_PER_THREAD)       // 4608 words = 18432 B
#define F4_PER_BLOCK (WORDS_PER_BLOCK / 4)               // 1152 float4

// 18432 B LDS/block -> 8 blocks/CU (147456 B of 160 KiB) -> 32 waves/CU
// (max occupancy), vs 4 blocks/16 waves for the old 36 KB variant.

typedef float f32x4 __attribute__((ext_vector_type(4)));

// One pixel's 9 outputs as named scalars -> SROA into VGPRs.
struct Px { float a00, a01, a02, a10, a11, a12, d0, d1, ff; };

__device__ __forceinline__ Px compute_px(
    float u0, float u1, float invf,
    float a0, float a1, float a2,
    float J00, float J01, float J10, float J11, float J21, float cp)
{
    const float c3 = a2;

    // proj = abc[:2] - c3*uv
    const float p0 = a0 - c3 * u0;
    const float p1 = a1 - c3 * u1;

    // J_norm2proj (2x2 symmetric): I/n - vvT/n^3
    const float n2     = p0 * p0 + p1 * p1;
    const float inv_n  = rsqrtf(n2);
    const float inv_n3 = inv_n * inv_n * inv_n;
    const float M00 = inv_n - p0 * p0 * inv_n3;
    const float M01 =        -p0 * p1 * inv_n3;
    const float M11 = inv_n - p1 * p1 * inv_n3;

    // J_proj2delta = [[1,0,-u0],[0,1,-u1]] @ J_rp   (J20 = 0)
    const float P00 = J00;
    const float P01 = J01 + u0 * cp;   // J01 - u0*J21
    const float P10 = J10;
    const float P11 = J11 + u1 * cp;

    Px r;
    // J_up2delta = M @ P
    r.a00 = M00 * P00 + M01 * P10;
    r.a01 = M00 * P01 + M01 * P11;
    r.a10 = M01 * P00 + M11 * P10;
    r.a11 = M01 * P01 + M11 * P11;

    // J_proj2f = c3*uv/f ;  J_up2f = M @ J_proj2f
    const float q0 = c3 * u0 * invf;
    const float q1 = c3 * u1 * invf;
    r.a02 = M00 * q0 + M01 * q1;
    r.a12 = M01 * q0 + M11 * q1;

    // uv1 = (u0,u1,1); its vecnorm jacobian pieces
    const float nn2     = u0 * u0 + u1 * u1 + 1.0f;
    const float inv_nn  = rsqrtf(nn2);
    const float inv_nn3 = inv_nn * inv_nn * inv_nn;

    // J_delta = uv1_norm @ J_rp   (J20 = 0)
    r.d0 = inv_nn * (u0 * J00 + u1 * J10);
    r.d1 = inv_nn * (u0 * J01 + u1 * J11 + J21);

    // J_norm2f = J_norm2img @ (-uv/f);  J_f = J_norm2f . abc
    const float w0 = -u0 * invf;
    const float w1 = -u1 * invf;
    const float s  = u0 * w0 + u1 * w1;
    const float g0 = inv_nn * w0 - u0 * inv_nn3 * s;
    const float g1 = inv_nn * w1 - u1 * inv_nn3 * s;
    const float g2 =             -      inv_nn3 * s;
    r.ff = g0 * a0 + g1 * a1 + g2 * a2;

    return r;
}

__global__ __launch_bounds__(BLOCK) void jac_kernel(
    const float* __restrict__ roll,
    const float* __restrict__ pitch,
    const float* __restrict__ focal,
    float* __restrict__ out)
{
    // Staging: phase-1 writes are ds_write_b64 at 18-word thread stride.
    // Bank check (b64, 16-lane phase): words (18*l + 2k) mod 32 — 18*l hits
    // each even residue exactly once for l=0..15, so each b64 phase touches
    // all 32 banks exactly once per 16 lanes => conflict-free floor.
    // Phase-2 reads are block-linear float4 (16B-aligned) => conflict-free.
    __shared__ float2 lds2[WORDS_PER_BLOCK / 2];     // 18432 B

    const int tid = threadIdx.x;
    const int t = blockIdx.x * BLOCK + tid;
    const int b = t >> 17;                          // t / THREADS_PER_BATCH
    const int pix0 = (t & (THREADS_PER_BATCH - 1)) * PIX_PER_THREAD;
    const int y  = pix0 >> 9;                       // / WW
    const int x0 = pix0 & (WW - 1);                 // even, never crosses a row

    // ---- per-batch constants ----
    const float rl = roll[b];
    const float pt = pitch[b];
    const float f  = focal[b];
    const float sr = sinf(rl), cr = cosf(rl);
    const float sp = sinf(pt), cp = cosf(pt);
    const float a0 = -sr * cp, a1 = -cr * cp, a2 = -sp;   // abc
    // J_rp (3x2): row0=(-cr*cp, sr*sp) row1=(sr*cp, cr*sp) row2=(0, -cp)
    const float J00 = -cr * cp, J01 = sr * sp;
    const float J10 =  sr * cp, J11 = cr * sp;
    const float J21 = -cp;                                 // J20 == 0
    const float invf = 1.0f / f;

    const float u1 = ((float)y  + 0.5f - (float)HH * 0.5f) * invf;
    const float ub = ((float)x0 + 0.5f - (float)WW * 0.5f) * invf;

    // ---- 2 pixels, all in named registers ----
    const Px A  = compute_px(ub,        u1, invf, a0, a1, a2, J00, J01, J10, J11, J21, cp);
    const Px Bx = compute_px(ub + invf, u1, invf, a0, a1, a2, J00, J01, J10, J11, J21, cp);

    // Phase 1: registers -> LDS (AoS, 9 float2 per thread, conflict-free)
    float2* s = &lds2[tid * 9];
    s[0] = make_float2(A.a00, A.a01);
    s[1] = make_float2(A.a02, A.a10);
    s[2] = make_float2(A.a11, A.a12);
    s[3] = make_float2(A.d0,  A.d1 );
    s[4] = make_float2(A.ff,  Bx.a00);
    s[5] = make_float2(Bx.a01, Bx.a02);
    s[6] = make_float2(Bx.a10, Bx.a11);
    s[7] = make_float2(Bx.a12, Bx.d0);
    s[8] = make_float2(Bx.d1,  Bx.ff);

    __syncthreads();

    // Phase 2: LDS -> global, block-linear float4, nontemporal (bypass L2
    // write-allocate; output is never re-read by this kernel).
    const f32x4* lv = (const f32x4*)lds2;
    f32x4* ob = (f32x4*)out + (size_t)blockIdx.x * F4_PER_BLOCK;
#pragma unroll
    for (int k = 0; k < 4; ++k) {
        const int idx = k * BLOCK + tid;
        __builtin_nontemporal_store(lv[idx], ob + idx);
    }
    // tail: 1152 - 4*256 = 128 float4
    if (tid < F4_PER_BLOCK - 4 * BLOCK) {
        const int idx = 4 * BLOCK + tid;
        __builtin_nontemporal_store(lv[idx], ob + idx);
    }
}

extern "C" void kernel_launch(void* const* d_in, const int* in_sizes, int n_in,
                              void* d_out, int out_size, void* d_ws, size_t ws_size,
                              hipStream_t stream) {
    const float* roll  = (const float*)d_in[0];
    const float* pitch = (const float*)d_in[1];
    const float* focal = (const float*)d_in[2];
    float* out = (float*)d_out;

    dim3 grid(TOTAL_THREADS / BLOCK);   // 8192
    dim3 block(BLOCK);
    jac_kernel<<<grid, block, 0, stream>>>(roll, pitch, focal, out);
}